// Round 17
// baseline (28.164 us; speedup 1.0000x reference)
//
#include <hip/hip_runtime.h>
#include <math.h>

#define BB 4
#define SS 4096
#define DD 256
#define WT_PLANE 65536  // halves per W1 fp16 plane (256x256)

typedef __attribute__((ext_vector_type(8))) _Float16 h8v;  // 8 fp16 (4 VGPRs)
typedef __attribute__((ext_vector_type(4))) float f4v;     // MFMA accumulator

// ---- fp16 split helpers (RNE; splitting lemma: a - (float)ah is exact) ----
__device__ __forceinline__ ushort f2h(float f) {
    _Float16 h = (_Float16)f;
    return __builtin_bit_cast(ushort, h);
}
__device__ __forceinline__ float h2f(ushort u) {
    return (float)__builtin_bit_cast(_Float16, u);
}
// 2-way fp16 split of two floats, packed: a = h + l + O(2^-23)
__device__ __forceinline__ void split2htwo(float a, float b, uint& h, uint& l) {
    const ushort ah = f2h(a);
    const ushort al = f2h(a - h2f(ah));
    const ushort bh = f2h(b);
    const ushort bl = f2h(b - h2f(bh));
    h = (uint)ah | ((uint)bh << 16);
    l = (uint)al | ((uint)bl << 16);
}

// ---------------------------------------------------------------------------
// K0 prep: 48 blocks x 256 thr (R16-verbatim).
//  blocks [0,32): q[b][h] = x[b,0,:] @ W0 (RoPE at pos 0 = identity);
//                 hc==0 zeroes y, hc==1 zeroes out (for atomics).
//  blocks [32,48): W1 (fp32 [k][c]) -> 2 RNE fp16 planes, MFMA-fragment-
//                  linear layout.
// ---------------------------------------------------------------------------
__global__ __launch_bounds__(256) void prep_kernel(const float* __restrict__ x,
                                                   const float* __restrict__ W0,
                                                   const float* __restrict__ W1,
                                                   float* __restrict__ q,
                                                   float* __restrict__ y,
                                                   float* __restrict__ out,
                                                   ushort* __restrict__ wt) {
    __shared__ float sh[64 * 65];
    const int bid = blockIdx.x;
    const int tid = threadIdx.x;

    if (bid < 32) {
        const int b = bid >> 3;
        const int hc = bid & 7;
        if (hc == 0) y[b * DD + tid] = 0.f;
        if (hc == 1) out[b * DD + tid] = 0.f;
        const int hk = tid & 31;
        const int iseg = tid >> 5;
        const int h = hc * 32 + hk;
        const float* xrow = x + (size_t)b * SS * DD;
        float p = 0.f;
#pragma unroll
        for (int k = 0; k < 32; ++k) {
            const int i = iseg * 32 + k;
            p = fmaf(xrow[i], W0[i * DD + h], p);
        }
        sh[tid] = p;
        __syncthreads();
        if (tid < 32) {
            float s = 0.f;
#pragma unroll
            for (int jj = 0; jj < 8; ++jj) s += sh[jj * 32 + tid];
            q[b * DD + hc * 32 + tid] = s;
        }
    } else {
        const int cb = bid - 32;
        const int k0 = (cb & 3) * 64;
        const int c0 = (cb >> 2) * 64;
        {
            const int kr = tid >> 2;
            const int csg = tid & 3;
            const float* src = W1 + (size_t)(k0 + kr) * DD + c0 + csg * 16;
#pragma unroll
            for (int i = 0; i < 4; ++i) {
                const float4 v = *(const float4*)(src + i * 4);
                sh[kr * 65 + csg * 16 + i * 4 + 0] = v.x;
                sh[kr * 65 + csg * 16 + i * 4 + 1] = v.y;
                sh[kr * 65 + csg * 16 + i * 4 + 2] = v.z;
                sh[kr * 65 + csg * 16 + i * 4 + 3] = v.w;
            }
        }
        __syncthreads();
        {
            const int cr = tid >> 2;
            const int ks2 = tid & 3;
            const int c = c0 + cr;
#pragma unroll
            for (int oct = 0; oct < 2; ++oct) {
                const int k = k0 + ks2 * 16 + oct * 8;
                const int kl = ks2 * 16 + oct * 8;
                uint H[4], L[4];
#pragma unroll
                for (int i = 0; i < 4; ++i) {
                    const float fa = sh[(kl + 2 * i + 0) * 65 + cr];
                    const float fb = sh[(kl + 2 * i + 1) * 65 + cr];
                    split2htwo(fa, fb, H[i], L[i]);
                }
                const size_t idx = ((size_t)(c >> 4) * 8 + (k >> 5)) * 512
                                 + (size_t)((k >> 3) & 3) * 128 + (size_t)(c & 15) * 8;
                *(uint4*)(wt + idx) = make_uint4(H[0], H[1], H[2], H[3]);
                *(uint4*)(wt + WT_PLANE + idx) = make_uint4(L[0], L[1], L[2], L[3]);
            }
        }
    }
}

// ---------------------------------------------------------------------------
// K1: scores[b][t] = q_b . R_t( x[b,t,:] @ W1 )  (2-way fp16 split, 3-pass
// MFMA). NEW: 32-row blocks, grid 512, 512 thr = 8 waves, ~69 KB LDS ->
// 2 blocks/CU so one block's MFMA overlaps the other's staging/trig phase
// (was 1 block/CU = fully serialized phases). Wave wv owns col-tiles
// 2wv, 2wv+1 over all 32 rows (acc[2][2]); per-(row,col-tile) MFMA chains,
// epilogue fmaf chains, and the 8-summand combine are bitwise R14-identical.
// cs table (32 t x 128 j) in LDS, bit-identical trig, overlapped with x
// staging. Softmax partials now per-32-chunk (128 per batch).
// ---------------------------------------------------------------------------
__global__ __launch_bounds__(512, 4) void scores_mfma(const float* __restrict__ x,
                                                      const ushort* __restrict__ wt,
                                                      const float* __restrict__ q,
                                                      float* __restrict__ scores,
                                                      float2* __restrict__ partials) {
    __shared__ __align__(16) unsigned char smem[32768];  // 2 planes x 32 rows x 512 B
    __shared__ __align__(16) float cs_lds[128 * 66];     // 33 KB (j-major, pad 66)
    __shared__ float scomb[8][32];
    __shared__ float q_s[256];
    const int tid = threadIdx.x;
    const int bid = blockIdx.x;
    const int b = bid >> 7;
    const int row0 = (bid & 127) << 5;  // 32-row block

    // ---- issue x loads to regs early (HBM latency covers the trig below) ----
    const int r = tid >> 4;    // 32 rows, 16 threads each
    const int seg = tid & 15;  // 16-float k segment
    const float* xr = x + ((size_t)(b * SS + row0 + r)) * DD + seg * 16;
    float4 xf0 = *(const float4*)(xr);
    float4 xf1 = *(const float4*)(xr + 4);
    float4 xf2 = *(const float4*)(xr + 8);
    float4 xf3 = *(const float4*)(xr + 12);

    // ---- cs slice gen: thread -> (j = tid>>2, 8 consecutive t) ----
    {
        const float kfac = (float)(-9.210340371976184 / 128.0);  // -ln(1e4)/128
        const int jj = tid >> 2;
        const int tl0 = (tid & 3) * 8;
        const float d = expf((float)jj * kfac);
        float* dst = cs_lds + jj * 66 + tl0 * 2;
#pragma unroll
        for (int e = 0; e < 8; ++e) {
            float sv, cv;
            sincosf((float)(row0 + tl0 + e) * d, &sv, &cv);
            dst[2 * e] = cv;
            dst[2 * e + 1] = sv;
        }
    }
    if (tid < 256) q_s[tid] = q[b * DD + tid];

    // ---- split x -> 2 fp16 planes, swizzled 16B slots ----
    {
        const int swz = (r & 15) << 4;
        uint H[4], L[4];
        split2htwo(xf0.x, xf0.y, H[0], L[0]);
        split2htwo(xf0.z, xf0.w, H[1], L[1]);
        split2htwo(xf1.x, xf1.y, H[2], L[2]);
        split2htwo(xf1.z, xf1.w, H[3], L[3]);
        int s = seg * 2;
        int off = r * 512 + (((s << 4)) ^ swz);
        *(uint4*)(smem + off) = make_uint4(H[0], H[1], H[2], H[3]);
        *(uint4*)(smem + 16384 + off) = make_uint4(L[0], L[1], L[2], L[3]);
        split2htwo(xf2.x, xf2.y, H[0], L[0]);
        split2htwo(xf2.z, xf2.w, H[1], L[1]);
        split2htwo(xf3.x, xf3.y, H[2], L[2]);
        split2htwo(xf3.z, xf3.w, H[3], L[3]);
        s = seg * 2 + 1;
        off = r * 512 + (((s << 4)) ^ swz);
        *(uint4*)(smem + off) = make_uint4(H[0], H[1], H[2], H[3]);
        *(uint4*)(smem + 16384 + off) = make_uint4(L[0], L[1], L[2], L[3]);
    }
    __syncthreads();

    const int lane = tid & 63;
    const int wv = tid >> 6;   // 0..7: pair of 16-col tiles
    const int l15 = lane & 15;
    const int hg = lane >> 4;  // 0..3

    f4v acc[2][2];  // [rt][ct]
#pragma unroll
    for (int rt = 0; rt < 2; ++rt)
#pragma unroll
        for (int ct = 0; ct < 2; ++ct) acc[rt][ct] = {0.f, 0.f, 0.f, 0.f};

    const ushort* wb = wt + (size_t)lane * 8;  // lane-linear fragment base
    const int aswz = l15 << 4;

#pragma unroll
    for (int ks = 0; ks < 8; ++ks) {
        h8v a_h[2], a_l[2];
#pragma unroll
        for (int rt = 0; rt < 2; ++rt) {
            const int row = rt * 16 + l15;
            const int off = row * 512 + ((((ks * 4 + hg) << 4)) ^ aswz);
            a_h[rt] = *(const h8v*)(smem + off);
            a_l[rt] = *(const h8v*)(smem + 16384 + off);
        }
#pragma unroll
        for (int ct = 0; ct < 2; ++ct) {
            const int gct = wv * 2 + ct;
            const ushort* bp = wb + (size_t)(gct * 8 + ks) * 512;
            const h8v b_h = *(const h8v*)(bp);
            const h8v b_l = *(const h8v*)(bp + WT_PLANE);
#pragma unroll
            for (int rt = 0; rt < 2; ++rt) {
                acc[rt][ct] = __builtin_amdgcn_mfma_f32_16x16x32_f16(a_h[rt], b_h, acc[rt][ct], 0, 0, 0);
                acc[rt][ct] = __builtin_amdgcn_mfma_f32_16x16x32_f16(a_h[rt], b_l, acc[rt][ct], 0, 0, 0);
                acc[rt][ct] = __builtin_amdgcn_mfma_f32_16x16x32_f16(a_l[rt], b_h, acc[rt][ct], 0, 0, 0);
            }
        }
    }

    // ---- epilogue: u from LDS cs + q; dot; 16-lane reduce; LDS combine ----
    const int par = l15 & 1;
    float p[2][4];
#pragma unroll
    for (int rt = 0; rt < 2; ++rt)
#pragma unroll
        for (int i = 0; i < 4; ++i) p[rt][i] = 0.f;

#pragma unroll
    for (int ct = 0; ct < 2; ++ct) {
        const int c = (wv * 2 + ct) * 16 + l15;
        const int j = c >> 1;
        const float qe = q_s[2 * j], qo = q_s[2 * j + 1];
        const float* csp = cs_lds + j * 66;
#pragma unroll
        for (int rt = 0; rt < 2; ++rt) {
            const int tloc = rt * 16 + hg * 4;
            const float4 csA = *(const float4*)(csp + tloc * 2);
            const float4 csB = *(const float4*)(csp + tloc * 2 + 4);
            const float u0 = par ? (qo * csA.x - qe * csA.y) : (qe * csA.x + qo * csA.y);
            const float u1 = par ? (qo * csA.z - qe * csA.w) : (qe * csA.z + qo * csA.w);
            const float u2 = par ? (qo * csB.x - qe * csB.y) : (qe * csB.x + qo * csB.y);
            const float u3 = par ? (qo * csB.z - qe * csB.w) : (qe * csB.z + qo * csB.w);
            p[rt][0] = fmaf(acc[rt][ct][0], u0, p[rt][0]);
            p[rt][1] = fmaf(acc[rt][ct][1], u1, p[rt][1]);
            p[rt][2] = fmaf(acc[rt][ct][2], u2, p[rt][2]);
            p[rt][3] = fmaf(acc[rt][ct][3], u3, p[rt][3]);
        }
    }
#pragma unroll
    for (int rt = 0; rt < 2; ++rt) {
#pragma unroll
        for (int off = 1; off <= 8; off <<= 1) {
            p[rt][0] += __shfl_xor(p[rt][0], off);
            p[rt][1] += __shfl_xor(p[rt][1], off);
            p[rt][2] += __shfl_xor(p[rt][2], off);
            p[rt][3] += __shfl_xor(p[rt][3], off);
        }
        if (l15 == 0)
            *(float4*)&scomb[wv][rt * 16 + hg * 4] = make_float4(p[rt][0], p[rt][1], p[rt][2], p[rt][3]);
    }
    __syncthreads();
    if (tid < 32) {
        float s = 0.f;
#pragma unroll
        for (int g = 0; g < 8; ++g) s += scomb[g][tid];
        scores[(size_t)b * SS + row0 + tid] = s;
        // ---- per-chunk softmax partials (m_c, S_c) over 32 lanes ----
        float m = s;
#pragma unroll
        for (int off = 16; off >= 1; off >>= 1) m = fmaxf(m, __shfl_xor(m, off));
        float sc = expf(s - m);
#pragma unroll
        for (int off = 16; off >= 1; off >>= 1) sc += __shfl_xor(sc, off);
        if (tid == 0) partials[b * 128 + (bid & 127)] = make_float2(m, sc);
    }
}

// ---------------------------------------------------------------------------
// K2 final_y: two-level softmax combine (128 partials, 2/lane) + weighted
// row-sum into y. grid (128 chunks of 32, 4 b), 1024 thr. ~126/128 blocks
// exit after the 1 KB partials read + 32-score check.
// ---------------------------------------------------------------------------
__global__ __launch_bounds__(1024) void final_y_kernel(const float* __restrict__ x,
                                                       const float* __restrict__ scores,
                                                       const float2* __restrict__ partials,
                                                       float* __restrict__ y) {
    const int c = blockIdx.x;   // 32-t chunk
    const int b = blockIdx.y;
    const int tid = threadIdx.x;
    __shared__ float a_s[32];
    __shared__ float yls[4][256];
    __shared__ float MS[2];
    __shared__ int flag;
    if (tid == 0) flag = 0;

    if (tid < 64) {  // wave 0: combine 128 partials, 2 per lane
        const float2 pa = partials[b * 128 + tid * 2];
        const float2 pb = partials[b * 128 + tid * 2 + 1];
        float m = fmaxf(pa.x, pb.x);
#pragma unroll
        for (int off = 32; off >= 1; off >>= 1) m = fmaxf(m, __shfl_xor(m, off));
        float sc = pa.y * expf(pa.x - m) + pb.y * expf(pb.x - m);
#pragma unroll
        for (int off = 32; off >= 1; off >>= 1) sc += __shfl_xor(sc, off);
        if (tid == 0) {
            MS[0] = m;
            MS[1] = sc;
        }
    }
    __syncthreads();
    const float M = MS[0];
    const float inv = 1.0f / MS[1];

    if (tid < 32) {
        const float a = expf(scores[(size_t)b * SS + (c << 5) + tid] - M) * inv;
        a_s[tid] = a;
        if (__any(a != 0.f) && tid == 0) flag = 1;
    }
    __syncthreads();
    if (!flag) return;  // block-uniform: whole chunk underflowed

    const int o = tid & 255;
    const int th = tid >> 8;  // 0..3
    float accv = 0.f;
#pragma unroll
    for (int t = th * 8; t < th * 8 + 8; ++t) {
        const float a = a_s[t];
        if (a != 0.f)
            accv = fmaf(a, x[((size_t)(b * SS + c * 32 + t)) * DD + o], accv);
    }
    yls[th][o] = accv;
    __syncthreads();
    if (tid < 256)
        atomicAdd(&y[b * DD + tid],
                  ((yls[0][tid] + yls[1][tid]) + yls[2][tid]) + yls[3][tid]);
}

// ---------------------------------------------------------------------------
// K3 out: out[b][o] += sum_{i in chunk} y[b][i] * W2[i][o].  grid (16, 4):
// 64 blocks spread the cold 256 KB W2 read across 64 CUs (R8-validated).
// ---------------------------------------------------------------------------
__global__ __launch_bounds__(256) void out_kernel(const float* __restrict__ y,
                                                  const float* __restrict__ W2,
                                                  float* __restrict__ out) {
    const int i0 = blockIdx.x * 16;
    const int b = blockIdx.y;
    const int o = threadIdx.x;
    __shared__ float y_s[16];
    if (o < 16) y_s[o] = y[b * DD + i0 + o];
    __syncthreads();
    float p = 0.f;
#pragma unroll
    for (int ii = 0; ii < 16; ++ii) p = fmaf(y_s[ii], W2[(size_t)(i0 + ii) * DD + o], p);
    atomicAdd(&out[b * DD + o], p);
}

// ---------------------------------------------------------------------------
extern "C" void kernel_launch(void* const* d_in, const int* in_sizes, int n_in,
                              void* d_out, int out_size, void* d_ws, size_t ws_size,
                              hipStream_t stream) {
    const float* x = (const float*)d_in[0];
    const float* W0 = (const float*)d_in[1];
    const float* W1 = (const float*)d_in[2];
    const float* W2 = (const float*)d_in[3];
    float* ws = (float*)d_ws;
    float* q = ws;                             // 1024 floats
    float* scores = ws + 1024;                 // 16384 floats
    float2* partials = (float2*)(ws + 17408);  // 512 float2
    float* y = ws + 18432;                     // 1024 floats
    ushort* wt = (ushort*)(ws + 19456);        // 2 planes x 65536 halves = 256 KB
    float* out = (float*)d_out;

    prep_kernel<<<dim3(48), 256, 0, stream>>>(x, W0, W1, q, y, out, wt);
    scores_mfma<<<dim3(512), 512, 0, stream>>>(x, wt, q, scores, partials);
    final_y_kernel<<<dim3(128, BB), 1024, 0, stream>>>(x, scores, partials, y);
    out_kernel<<<dim3(16, BB), 256, 0, stream>>>(y, W2, out);
}

// Round 18
// 26.620 us; speedup vs baseline: 1.0580x; 1.0580x over previous
//
#include <hip/hip_runtime.h>
#include <math.h>

#define BB 4
#define SS 4096
#define DD 256
#define WT_PLANE 65536  // halves per W1 fp16 plane (256x256)

typedef __attribute__((ext_vector_type(8))) _Float16 h8v;  // 8 fp16 (4 VGPRs)
typedef __attribute__((ext_vector_type(4))) float f4v;     // MFMA accumulator

// ---- fp16 split helpers (RNE; splitting lemma: a - (float)ah is exact) ----
__device__ __forceinline__ ushort f2h(float f) {
    _Float16 h = (_Float16)f;
    return __builtin_bit_cast(ushort, h);
}
__device__ __forceinline__ float h2f(ushort u) {
    return (float)__builtin_bit_cast(_Float16, u);
}
// 2-way fp16 split of two floats, packed: a = h + l + O(2^-23)
__device__ __forceinline__ void split2htwo(float a, float b, uint& h, uint& l) {
    const ushort ah = f2h(a);
    const ushort al = f2h(a - h2f(ah));
    const ushort bh = f2h(b);
    const ushort bl = f2h(b - h2f(bh));
    h = (uint)ah | ((uint)bh << 16);
    l = (uint)al | ((uint)bl << 16);
}

// ---------------------------------------------------------------------------
// K0 prep: 48 blocks x 256 thr (R16-verbatim).
//  blocks [0,32): q[b][h] = x[b,0,:] @ W0 (RoPE at pos 0 = identity);
//                 hc==0 zeroes y, hc==1 zeroes out (for atomics).
//  blocks [32,48): W1 (fp32 [k][c]) -> 2 RNE fp16 planes, MFMA-fragment-
//                  linear layout.
// ---------------------------------------------------------------------------
__global__ __launch_bounds__(256) void prep_kernel(const float* __restrict__ x,
                                                   const float* __restrict__ W0,
                                                   const float* __restrict__ W1,
                                                   float* __restrict__ q,
                                                   float* __restrict__ y,
                                                   float* __restrict__ out,
                                                   ushort* __restrict__ wt) {
    __shared__ float sh[64 * 65];
    const int bid = blockIdx.x;
    const int tid = threadIdx.x;

    if (bid < 32) {
        const int b = bid >> 3;
        const int hc = bid & 7;
        if (hc == 0) y[b * DD + tid] = 0.f;
        if (hc == 1) out[b * DD + tid] = 0.f;
        const int hk = tid & 31;
        const int iseg = tid >> 5;
        const int h = hc * 32 + hk;
        const float* xrow = x + (size_t)b * SS * DD;
        float p = 0.f;
#pragma unroll
        for (int k = 0; k < 32; ++k) {
            const int i = iseg * 32 + k;
            p = fmaf(xrow[i], W0[i * DD + h], p);
        }
        sh[tid] = p;
        __syncthreads();
        if (tid < 32) {
            float s = 0.f;
#pragma unroll
            for (int jj = 0; jj < 8; ++jj) s += sh[jj * 32 + tid];
            q[b * DD + hc * 32 + tid] = s;
        }
    } else {
        const int cb = bid - 32;
        const int k0 = (cb & 3) * 64;
        const int c0 = (cb >> 2) * 64;
        {
            const int kr = tid >> 2;
            const int csg = tid & 3;
            const float* src = W1 + (size_t)(k0 + kr) * DD + c0 + csg * 16;
#pragma unroll
            for (int i = 0; i < 4; ++i) {
                const float4 v = *(const float4*)(src + i * 4);
                sh[kr * 65 + csg * 16 + i * 4 + 0] = v.x;
                sh[kr * 65 + csg * 16 + i * 4 + 1] = v.y;
                sh[kr * 65 + csg * 16 + i * 4 + 2] = v.z;
                sh[kr * 65 + csg * 16 + i * 4 + 3] = v.w;
            }
        }
        __syncthreads();
        {
            const int cr = tid >> 2;
            const int ks2 = tid & 3;
            const int c = c0 + cr;
#pragma unroll
            for (int oct = 0; oct < 2; ++oct) {
                const int k = k0 + ks2 * 16 + oct * 8;
                const int kl = ks2 * 16 + oct * 8;
                uint H[4], L[4];
#pragma unroll
                for (int i = 0; i < 4; ++i) {
                    const float fa = sh[(kl + 2 * i + 0) * 65 + cr];
                    const float fb = sh[(kl + 2 * i + 1) * 65 + cr];
                    split2htwo(fa, fb, H[i], L[i]);
                }
                const size_t idx = ((size_t)(c >> 4) * 8 + (k >> 5)) * 512
                                 + (size_t)((k >> 3) & 3) * 128 + (size_t)(c & 15) * 8;
                *(uint4*)(wt + idx) = make_uint4(H[0], H[1], H[2], H[3]);
                *(uint4*)(wt + WT_PLANE + idx) = make_uint4(L[0], L[1], L[2], L[3]);
            }
        }
    }
}

// ---------------------------------------------------------------------------
// K1: scores[b][t] = q_b . R_t( x[b,t,:] @ W1 )  (2-way fp16 split, 3-pass
// MFMA) — R16-verbatim body (best measured: 26.76 us) + ks=0 B-fragment
// register prefetch issued BEFORE the staging barrier (values bitwise
// identical; overlaps the first post-barrier L2 stall with staging).
// grid 256 (4 b x 64 blocks of 64 rows), 1024 thr = 16 waves, wave (rh, cg).
// cs table generated in LDS (bit-identical trig), overlapped with x staging.
// Per-chunk softmax-partials tail (m_c, S_c) for the two-level softmax.
// ---------------------------------------------------------------------------
__global__ __launch_bounds__(1024, 4) void scores_mfma(const float* __restrict__ x,
                                                       const ushort* __restrict__ wt,
                                                       const float* __restrict__ q,
                                                       float* __restrict__ scores,
                                                       float2* __restrict__ partials) {
    __shared__ __align__(16) unsigned char smem[65536];  // 2 planes x 64 rows x 512 B
    __shared__ __align__(16) float cs_lds[128 * 132];    // 66 KB (j-major, pad 132)
    __shared__ float scomb[8][64];
    __shared__ float q_s[256];
    const int tid = threadIdx.x;
    const int bid = blockIdx.x;
    const int b = bid >> 6;
    const int row0 = (bid & 63) << 6;  // 64-row block

    // ---- issue x loads to regs early (HBM latency covers the trig below) ----
    const int r = tid >> 4;    // 64 rows, 16 threads each
    const int seg = tid & 15;  // 16-float k segment
    const float* xr = x + ((size_t)(b * SS + row0 + r)) * DD + seg * 16;
    float4 xf0 = *(const float4*)(xr);
    float4 xf1 = *(const float4*)(xr + 4);
    float4 xf2 = *(const float4*)(xr + 8);
    float4 xf3 = *(const float4*)(xr + 12);

    // ---- wave identity (needed for B prefetch) ----
    const int lane = tid & 63;
    const int wv = tid >> 6;   // 0..15
    const int rh = wv >> 3;    // row half (32 rows)
    const int cg = wv & 7;     // 32-col group
    const int l15 = lane & 15;
    const int hg = lane >> 4;  // 0..3
    const ushort* wb = wt + (size_t)lane * 8;  // lane-linear fragment base

    // ---- prefetch ks=0 B fragments (independent of staging) ----
    h8v pb_h[2], pb_l[2];
#pragma unroll
    for (int ct = 0; ct < 2; ++ct) {
        const ushort* bp = wb + (size_t)((cg * 2 + ct) * 8 + 0) * 512;
        pb_h[ct] = *(const h8v*)(bp);
        pb_l[ct] = *(const h8v*)(bp + WT_PLANE);
    }

    // ---- cs slice gen: thread -> (j = tid>>3, 8 consecutive t) ----
    {
        const float kfac = (float)(-9.210340371976184 / 128.0);  // -ln(1e4)/128
        const int jj = tid >> 3;
        const int tl0 = (tid & 7) * 8;
        const float d = expf((float)jj * kfac);
        float* dst = cs_lds + jj * 132 + tl0 * 2;
#pragma unroll
        for (int e = 0; e < 8; ++e) {
            float sv, cv;
            sincosf((float)(row0 + tl0 + e) * d, &sv, &cv);
            dst[2 * e] = cv;
            dst[2 * e + 1] = sv;
        }
    }
    if (tid < 256) q_s[tid] = q[b * DD + tid];

    // ---- split x -> 2 fp16 planes, swizzled 16B slots ----
    {
        const int swz = (r & 15) << 4;
        uint H[4], L[4];
        split2htwo(xf0.x, xf0.y, H[0], L[0]);
        split2htwo(xf0.z, xf0.w, H[1], L[1]);
        split2htwo(xf1.x, xf1.y, H[2], L[2]);
        split2htwo(xf1.z, xf1.w, H[3], L[3]);
        int s = seg * 2;
        int off = r * 512 + (((s << 4)) ^ swz);
        *(uint4*)(smem + off) = make_uint4(H[0], H[1], H[2], H[3]);
        *(uint4*)(smem + 32768 + off) = make_uint4(L[0], L[1], L[2], L[3]);
        split2htwo(xf2.x, xf2.y, H[0], L[0]);
        split2htwo(xf2.z, xf2.w, H[1], L[1]);
        split2htwo(xf3.x, xf3.y, H[2], L[2]);
        split2htwo(xf3.z, xf3.w, H[3], L[3]);
        s = seg * 2 + 1;
        off = r * 512 + (((s << 4)) ^ swz);
        *(uint4*)(smem + off) = make_uint4(H[0], H[1], H[2], H[3]);
        *(uint4*)(smem + 32768 + off) = make_uint4(L[0], L[1], L[2], L[3]);
    }
    __syncthreads();

    f4v acc[2][2];  // [rt][ct]
#pragma unroll
    for (int rt = 0; rt < 2; ++rt)
#pragma unroll
        for (int ct = 0; ct < 2; ++ct) acc[rt][ct] = {0.f, 0.f, 0.f, 0.f};

    const int aswz = l15 << 4;

#pragma unroll
    for (int ks = 0; ks < 8; ++ks) {
        h8v a_h[2], a_l[2];
#pragma unroll
        for (int rt = 0; rt < 2; ++rt) {
            const int row = rh * 32 + rt * 16 + l15;
            const int off = row * 512 + ((((ks * 4 + hg) << 4)) ^ aswz);
            a_h[rt] = *(const h8v*)(smem + off);
            a_l[rt] = *(const h8v*)(smem + 32768 + off);
        }
#pragma unroll
        for (int ct = 0; ct < 2; ++ct) {
            h8v b_h, b_l;
            if (ks == 0) {
                b_h = pb_h[ct];
                b_l = pb_l[ct];
            } else {
                const int gct = cg * 2 + ct;
                const ushort* bp = wb + (size_t)(gct * 8 + ks) * 512;
                b_h = *(const h8v*)(bp);
                b_l = *(const h8v*)(bp + WT_PLANE);
            }
#pragma unroll
            for (int rt = 0; rt < 2; ++rt) {
                acc[rt][ct] = __builtin_amdgcn_mfma_f32_16x16x32_f16(a_h[rt], b_h, acc[rt][ct], 0, 0, 0);
                acc[rt][ct] = __builtin_amdgcn_mfma_f32_16x16x32_f16(a_h[rt], b_l, acc[rt][ct], 0, 0, 0);
                acc[rt][ct] = __builtin_amdgcn_mfma_f32_16x16x32_f16(a_l[rt], b_h, acc[rt][ct], 0, 0, 0);
            }
        }
    }

    // ---- epilogue: u from LDS cs + q; dot; 16-lane reduce; LDS combine ----
    const int par = l15 & 1;
    float p[2][4];
#pragma unroll
    for (int rt = 0; rt < 2; ++rt)
#pragma unroll
        for (int i = 0; i < 4; ++i) p[rt][i] = 0.f;

#pragma unroll
    for (int ct = 0; ct < 2; ++ct) {
        const int c = (cg * 2 + ct) * 16 + l15;
        const int j = c >> 1;
        const float qe = q_s[2 * j], qo = q_s[2 * j + 1];
        const float* csp = cs_lds + j * 132;
#pragma unroll
        for (int rt = 0; rt < 2; ++rt) {
            const int tloc = rh * 32 + rt * 16 + hg * 4;
            const float4 csA = *(const float4*)(csp + tloc * 2);
            const float4 csB = *(const float4*)(csp + tloc * 2 + 4);
            const float u0 = par ? (qo * csA.x - qe * csA.y) : (qe * csA.x + qo * csA.y);
            const float u1 = par ? (qo * csA.z - qe * csA.w) : (qe * csA.z + qo * csA.w);
            const float u2 = par ? (qo * csB.x - qe * csB.y) : (qe * csB.x + qo * csB.y);
            const float u3 = par ? (qo * csB.z - qe * csB.w) : (qe * csB.z + qo * csB.w);
            p[rt][0] = fmaf(acc[rt][ct][0], u0, p[rt][0]);
            p[rt][1] = fmaf(acc[rt][ct][1], u1, p[rt][1]);
            p[rt][2] = fmaf(acc[rt][ct][2], u2, p[rt][2]);
            p[rt][3] = fmaf(acc[rt][ct][3], u3, p[rt][3]);
        }
    }
#pragma unroll
    for (int rt = 0; rt < 2; ++rt) {
#pragma unroll
        for (int off = 1; off <= 8; off <<= 1) {
            p[rt][0] += __shfl_xor(p[rt][0], off);
            p[rt][1] += __shfl_xor(p[rt][1], off);
            p[rt][2] += __shfl_xor(p[rt][2], off);
            p[rt][3] += __shfl_xor(p[rt][3], off);
        }
        if (l15 == 0)
            *(float4*)&scomb[cg][rh * 32 + rt * 16 + hg * 4] =
                make_float4(p[rt][0], p[rt][1], p[rt][2], p[rt][3]);
    }
    __syncthreads();
    if (tid < 64) {  // exactly wave 0
        float s = 0.f;
#pragma unroll
        for (int g = 0; g < 8; ++g) s += scomb[g][tid];
        scores[(size_t)b * SS + row0 + tid] = s;
        // ---- per-chunk softmax partials (m_c, S_c) ----
        float m = s;
#pragma unroll
        for (int off = 32; off >= 1; off >>= 1) m = fmaxf(m, __shfl_xor(m, off));
        float sc = expf(s - m);
#pragma unroll
        for (int off = 32; off >= 1; off >>= 1) sc += __shfl_xor(sc, off);
        if (tid == 0) partials[(b << 6) + (bid & 63)] = make_float2(m, sc);
    }
}

// ---------------------------------------------------------------------------
// K2 final_y: two-level softmax combine + weighted row-sum into y
// (R16-verbatim). grid (64 chunks, 4 b), 1024 thr. ~63/64 blocks exit after
// the 512 B partials read + 64-score check.
// ---------------------------------------------------------------------------
__global__ __launch_bounds__(1024) void final_y_kernel(const float* __restrict__ x,
                                                       const float* __restrict__ scores,
                                                       const float2* __restrict__ partials,
                                                       float* __restrict__ y) {
    const int c = blockIdx.x;
    const int b = blockIdx.y;
    const int tid = threadIdx.x;
    __shared__ float a_s[64];
    __shared__ float yls[4][256];
    __shared__ float MS[2];
    __shared__ int flag;
    if (tid == 0) flag = 0;

    if (tid < 64) {  // wave 0: combine partials
        const float2 pp = partials[(b << 6) + tid];
        float m = pp.x;
#pragma unroll
        for (int off = 32; off >= 1; off >>= 1) m = fmaxf(m, __shfl_xor(m, off));
        float sc = pp.y * expf(pp.x - m);
#pragma unroll
        for (int off = 32; off >= 1; off >>= 1) sc += __shfl_xor(sc, off);
        if (tid == 0) {
            MS[0] = m;
            MS[1] = sc;
        }
    }
    __syncthreads();
    const float M = MS[0];
    const float inv = 1.0f / MS[1];

    if (tid < 64) {
        const float a = expf(scores[(size_t)b * SS + (c << 6) + tid] - M) * inv;
        a_s[tid] = a;
        if (__any(a != 0.f) && tid == 0) flag = 1;
    }
    __syncthreads();
    if (!flag) return;  // block-uniform: whole chunk underflowed

    const int o = tid & 255;
    const int th = tid >> 8;  // 0..3
    float accv = 0.f;
#pragma unroll
    for (int t = th * 16; t < th * 16 + 16; ++t) {
        const float a = a_s[t];
        if (a != 0.f)
            accv = fmaf(a, x[((size_t)(b * SS + c * 64 + t)) * DD + o], accv);
    }
    yls[th][o] = accv;
    __syncthreads();
    if (tid < 256)
        atomicAdd(&y[b * DD + tid],
                  ((yls[0][tid] + yls[1][tid]) + yls[2][tid]) + yls[3][tid]);
}

// ---------------------------------------------------------------------------
// K3 out: out[b][o] += sum_{i in chunk} y[b][i] * W2[i][o].  grid (16, 4):
// 64 blocks spread the cold 256 KB W2 read across 64 CUs (R8-validated).
// ---------------------------------------------------------------------------
__global__ __launch_bounds__(256) void out_kernel(const float* __restrict__ y,
                                                  const float* __restrict__ W2,
                                                  float* __restrict__ out) {
    const int i0 = blockIdx.x * 16;
    const int b = blockIdx.y;
    const int o = threadIdx.x;
    __shared__ float y_s[16];
    if (o < 16) y_s[o] = y[b * DD + i0 + o];
    __syncthreads();
    float p = 0.f;
#pragma unroll
    for (int ii = 0; ii < 16; ++ii) p = fmaf(y_s[ii], W2[(size_t)(i0 + ii) * DD + o], p);
    atomicAdd(&out[b * DD + o], p);
}

// ---------------------------------------------------------------------------
extern "C" void kernel_launch(void* const* d_in, const int* in_sizes, int n_in,
                              void* d_out, int out_size, void* d_ws, size_t ws_size,
                              hipStream_t stream) {
    const float* x = (const float*)d_in[0];
    const float* W0 = (const float*)d_in[1];
    const float* W1 = (const float*)d_in[2];
    const float* W2 = (const float*)d_in[3];
    float* ws = (float*)d_ws;
    float* q = ws;                             // 1024 floats
    float* scores = ws + 1024;                 // 16384 floats
    float2* partials = (float2*)(ws + 17408);  // 256 float2
    float* y = ws + 17920;                     // 1024 floats
    ushort* wt = (ushort*)(ws + 18944);        // 2 planes x 65536 halves = 256 KB
    float* out = (float*)d_out;

    prep_kernel<<<dim3(48), 256, 0, stream>>>(x, W0, W1, q, y, out, wt);
    scores_mfma<<<dim3(256), 1024, 0, stream>>>(x, wt, q, scores, partials);
    final_y_kernel<<<dim3(64, BB), 1024, 0, stream>>>(x, scores, partials, y);
    out_kernel<<<dim3(16, BB), 256, 0, stream>>>(y, W2, out);
}